// Round 3
// baseline (265.668 us; speedup 1.0000x reference)
//
#include <hip/hip_runtime.h>

#define NB 147456   // C*C*KH*KW per sample
#define ZD 256
#define BSZ 32
#define CCH 128

typedef __attribute__((ext_vector_type(8))) short short8;
typedef __attribute__((ext_vector_type(16))) float floatx16;

__device__ __forceinline__ unsigned short f2bf(float f) {
    unsigned int u = __float_as_uint(f);
    return (unsigned short)((u + 0x7fffu + ((u >> 16) & 1u)) >> 16);
}
// pack hi16(lo),hi16(hi) -> one dword (two bf16, truncating convert)
__device__ __forceinline__ unsigned pk(unsigned hi, unsigned lo) {
    return __builtin_amdgcn_perm(hi, lo, 0x07060302u);
}

// ---- K1: h = relu(z@W+b); BN over batch; affine; bf16 Wk natural [b][n] -----------------------
// MFMA 32x32x16, M=32 batch. Wave = 128 cols as 4 interleaved tiles (tile t = cols 4*L+t):
// B stream is global_load_dwordx4 (16 B/lane), depth-2 prefetch (16 KB in flight/wave).
// 64-thr blocks x 1152: 4.5 waves/CU, 1.11x tail. BW floor ~24 us (151 MB dw read).
__global__ __launch_bounds__(64) void hyper_mfma(
    const float* __restrict__ z, const float* __restrict__ dw,
    const float* __restrict__ db, const float* __restrict__ gamma,
    const float* __restrict__ beta, unsigned short* __restrict__ wkn)
{
    int lane = threadIdx.x;                   // one wave per block
    int L = lane & 31;
    int klane = lane >> 5;
    int n0 = blockIdx.x * 128 + 4 * L;        // this lane's col group; tile t owns n0+t

    // A-frags: afrag[s] = z[m=L][s*16 + klane*8 .. +7] as bf16
    short8 afrag[16];
    const float* zp = z + L * 256 + klane * 8;
#pragma unroll
    for (int s = 0; s < 16; s++) {
        float4 a0 = *(const float4*)(zp + s * 16);
        float4 a1 = *(const float4*)(zp + s * 16 + 4);
        uint4 u;
        u.x = pk(__float_as_uint(a0.y), __float_as_uint(a0.x));
        u.y = pk(__float_as_uint(a0.w), __float_as_uint(a0.z));
        u.z = pk(__float_as_uint(a1.y), __float_as_uint(a1.x));
        u.w = pk(__float_as_uint(a1.w), __float_as_uint(a1.z));
        afrag[s] = *(short8*)&u;
    }

    floatx16 acc[4];
#pragma unroll
    for (int t = 0; t < 4; t++)
#pragma unroll
        for (int r = 0; r < 16; r++) acc[t][r] = 0.f;

    const float* dwp = dw + (size_t)(klane * 8) * NB + n0;

    unsigned ba[8][4], bb[8][4];
#define LOADB(BUF, S)                                                         \
    _Pragma("unroll") for (int j = 0; j < 8; j++)                             \
        *(uint4*)&BUF[j][0] = *(const uint4*)(dwp + (size_t)((S) * 16 + j) * NB);
#define DOMFMA(BUF, S)                                                        \
    _Pragma("unroll") for (int t = 0; t < 4; t++) {                           \
        uint4 u;                                                              \
        u.x = pk(BUF[1][t], BUF[0][t]); u.y = pk(BUF[3][t], BUF[2][t]);       \
        u.z = pk(BUF[5][t], BUF[4][t]); u.w = pk(BUF[7][t], BUF[6][t]);       \
        acc[t] = __builtin_amdgcn_mfma_f32_32x32x16_bf16(                     \
            afrag[S], *(short8*)&u, acc[t], 0, 0, 0);                         \
    }
    LOADB(ba, 0)
#pragma unroll
    for (int s = 0; s < 16; s += 2) {
        LOADB(bb, s + 1)
        DOMFMA(ba, s)
        if (s + 2 < 16) LOADB(ba, s + 2)
        DOMFMA(bb, s + 1)
    }
#undef LOADB
#undef DOMFMA

    // BN epilogue per tile-column; rows split between lane and lane^32
    float4 bias = *(const float4*)(db + n0);
    float4 gmm  = *(const float4*)(gamma + n0);
    float4 btt  = *(const float4*)(beta + n0);
    float bias_a[4] = { bias.x, bias.y, bias.z, bias.w };
    float gm_a[4]   = { gmm.x, gmm.y, gmm.z, gmm.w };
    float bt_a[4]   = { btt.x, btt.y, btt.z, btt.w };

    float sc_a[4], mn_a[4];
#pragma unroll
    for (int t = 0; t < 4; t++) {
        float sp = 0.f, qp = 0.f;
#pragma unroll
        for (int r = 0; r < 16; r++) {
            float v = fmaxf(acc[t][r] + bias_a[t], 0.f);
            acc[t][r] = v;
            sp += v; qp += v * v;
        }
        sp += __shfl_xor(sp, 32, 64);
        qp += __shfl_xor(qp, 32, 64);
        float mn = sp * (1.f / 32.f);
        float var = fmaxf(qp * (1.f / 32.f) - mn * mn, 0.f);
        mn_a[t] = mn;
        sc_a[t] = gm_a[t] / (sqrtf(var) + 1e-6f);
    }

#pragma unroll
    for (int r = 0; r < 16; r++) {
        int brow = (r & 3) + 8 * (r >> 2) + 4 * klane;
        float w0 = sc_a[0] * (acc[0][r] - mn_a[0]) + bt_a[0];
        float w1 = sc_a[1] * (acc[1][r] - mn_a[1]) + bt_a[1];
        float w2 = sc_a[2] * (acc[2][r] - mn_a[2]) + bt_a[2];
        float w3 = sc_a[3] * (acc[3][r] - mn_a[3]) + bt_a[3];
        uint2 o;
        o.x = (unsigned)f2bf(w0) | ((unsigned)f2bf(w1) << 16);
        o.y = (unsigned)f2bf(w2) | ((unsigned)f2bf(w3) << 16);
        *(uint2*)&wkn[(size_t)brow * NB + n0] = o;
    }
}

// ---- fused: blocks 0..255 repack wkn->wkt; blocks 256..1279 transpose x -> xT bf16 -----------
// wkt layout: [b][uv][ko(16 s-chunks)][f(128)] short8 -> conv A-loads fully coalesced (512B runs)
// xb16 layout: [b][p][ch(16 s-chunks)][q(32)] short8 -> conv LDS staging + reads conflict-free
__global__ __launch_bounds__(256) void repack_xt(
    const unsigned short* __restrict__ wkn, unsigned short* __restrict__ wkt,
    const float* __restrict__ x, unsigned short* __restrict__ xb16)
{
    __shared__ char lmem[16 * 580 * 4];
    int t = threadIdx.x;
    if (blockIdx.x < 256) {
        unsigned int* lt = (unsigned int*)lmem;   // [16][580]
        int b = blockIdx.x >> 3;
        int s0 = (blockIdx.x & 7) * 16;
        const unsigned int* src = (const unsigned int*)wkn + ((size_t)b * NB >> 1) + (size_t)s0 * 576;
#pragma unroll
        for (int i = 0; i < 36; i++) {
            int idx = t + i * 256;
            int si = idx / 576;
            int j2 = idx - si * 576;
            lt[si * 580 + j2] = src[(size_t)si * 576 + j2];
        }
        __syncthreads();
        const unsigned short* ls = (const unsigned short*)lt;
#pragma unroll
        for (int i = 0; i < 9; i++) {
            int tau = t + i * 256;                // 0..2303
            int f = tau & 127;                    // lane-consecutive -> coalesced write
            int half = (tau >> 7) & 1;
            int uv = tau >> 8;                    // 0..8
            int col = f * 9 + uv;
            unsigned short v[8];
#pragma unroll
            for (int ss = 0; ss < 8; ss++)
                v[ss] = ls[(half * 8 + ss) * 1160 + col];
            uint4 o;
            o.x = v[0] | ((unsigned)v[1] << 16);
            o.y = v[2] | ((unsigned)v[3] << 16);
            o.z = v[4] | ((unsigned)v[5] << 16);
            o.w = v[6] | ((unsigned)v[7] << 16);
            ((uint4*)wkt)[((((size_t)b * 9 + uv) * 16) + (s0 >> 3) + half) * 128 + f] = o;
        }
    } else {
        unsigned short* lx = (unsigned short*)lmem;   // [32][130]
        int idx = blockIdx.x - 256;
        int p = idx & 31;
        int b = idx >> 5;
        const float* xp = x + (size_t)b * CCH * 1024 + p * 32;
#pragma unroll
        for (int i = 0; i < 16; i++) {
            int ii = t + i * 256;
            int s = ii >> 5;
            int q = ii & 31;
            lx[q * 130 + s] = f2bf(xp[(size_t)s * 1024 + q]);
        }
        __syncthreads();
#pragma unroll
        for (int i = 0; i < 2; i++) {
            int tau = t + i * 256;                // 0..511
            int q = tau & 31;                     // lane-consecutive -> coalesced write
            int ch = tau >> 5;                    // 0..15
            const unsigned short* r = &lx[q * 130 + ch * 8];
            uint4 o;
            o.x = r[0] | ((unsigned)r[1] << 16);
            o.y = r[2] | ((unsigned)r[3] << 16);
            o.z = r[4] | ((unsigned)r[5] << 16);
            o.w = r[6] | ((unsigned)r[7] << 16);
            ((uint4*)xb16)[(((size_t)b * 32 + p) * 16 + ch) * 32 + q] = o;
        }
    }
}

// ---- conv: 1024 blocks (4/CU) x 128 thr = 2 waves; wave = 32f x 2p; p-tile = 2 rows ----------
// A-traffic halved vs p=1 (each A-load feeds 2 rows); 6 MFMA share 4 ds_read_b128 per step
// (1.5:1 vs 1:1). Depth-2 A prefetch (3 rotating bufs) covers L2 latency at 2 waves/SIMD.
// LDS [r=4][ch=16][col=34] = 34.8 KB -> 4 blocks/CU (139 KB). br reads conflict-free b128.
// XCD-swizzled: 4 samples/XCD (wkt slice L2-resident).
__global__ __launch_bounds__(128, 2) void conv_mfma(
    const float* __restrict__ x, const unsigned short* __restrict__ xb16,
    const unsigned short* __restrict__ wkt, const float* __restrict__ cb,
    float* __restrict__ out)
{
    __shared__ short8 lds8[4 * 16 * 34];      // [r=4][ch=16][col=34]
    int t = threadIdx.x;                      // 0..127
    int w = blockIdx.x;                       // 1024 blocks
    int xcd = w & 7, slot = w >> 3;           // 128 slots/XCD
    int b = (xcd << 2) | (slot & 3);          // 4 samples/XCD
    int rest = slot >> 2;                     // 0..31
    int fh = rest & 1;                        // f-half of this block
    int p0 = (rest >> 1) * 2;                 // 16 p-tiles of 2 rows
    int wid = t >> 6, lane = t & 63;
    int fbase = fh * 64 + wid * 32;           // each wave owns a distinct f-quarter
    int qcol = lane & 31, klane = lane >> 5;

    {                                         // zero halo cols 0 and 33 (4 rows x 16 ch x 2)
        int r = t >> 5;
        int ch = (t >> 1) & 15;
        int col = (t & 1) * 33;
        short8 zz = { 0, 0, 0, 0, 0, 0, 0, 0 };
        lds8[(r * 16 + ch) * 34 + col] = zz;
    }
    const uint4* xsrc = (const uint4*)xb16;
#pragma unroll
    for (int i = 0; i < 16; i++) {            // stage 4 rows x 16 ch x 32 q = 2048 uint4
        int tau = t + i * 128;
        int q = tau & 31;
        int ch = (tau >> 5) & 15;
        int r = tau >> 9;                     // 0..3
        int prow = p0 - 1 + r;
        uint4 v = make_uint4(0, 0, 0, 0);
        if (prow >= 0 && prow < 32)
            v = xsrc[(((size_t)b * 32 + prow) * 16 + ch) * 32 + q];
        *(uint4*)&lds8[(r * 16 + ch) * 34 + q + 1] = v;
    }
    __syncthreads();

    floatx16 acc[2];
#pragma unroll
    for (int ni = 0; ni < 2; ni++)
#pragma unroll
        for (int r = 0; r < 16; r++) acc[ni][r] = 0.f;

    const short8* A8 = (const short8*)wkt + ((size_t)b * 9 << 11);
    short8 A0[3], A1[3], A2[3];

#define LOAD3(BUF, ST)                                                        \
    {                                                                         \
        int v_ = (ST) >> 3, ks_ = (ST) & 7;                                   \
        int ko_ = ks_ * 2 + klane;                                            \
        _Pragma("unroll") for (int u_ = 0; u_ < 3; u_++)                      \
            BUF[u_] = A8[(((size_t)(u_ * 3 + v_) * 16 + ko_) << 7) + fbase + qcol]; \
    }
#define COMPUTE(BUF, ST)                                                      \
    {                                                                         \
        int v_ = (ST) >> 3, ks_ = (ST) & 7;                                   \
        int ko_ = ks_ * 2 + klane;                                            \
        short8 br[4];                                                         \
        _Pragma("unroll") for (int r_ = 0; r_ < 4; r_++)                      \
            br[r_] = lds8[(r_ * 16 + ko_) * 34 + qcol + v_];                  \
        _Pragma("unroll") for (int u_ = 0; u_ < 3; u_++) {                    \
            acc[0] = __builtin_amdgcn_mfma_f32_32x32x16_bf16(                 \
                BUF[u_], br[u_], acc[0], 0, 0, 0);                            \
            acc[1] = __builtin_amdgcn_mfma_f32_32x32x16_bf16(                 \
                BUF[u_], br[u_ + 1], acc[1], 0, 0, 0);                        \
        }                                                                     \
    }

    LOAD3(A0, 0)
    LOAD3(A1, 1)
#pragma unroll
    for (int st = 0; st < 24; st += 3) {
        LOAD3(A2, st + 2)
        COMPUTE(A0, st)
        if (st + 3 < 24) LOAD3(A0, st + 3)
        COMPUTE(A1, st + 1)
        if (st + 4 < 24) LOAD3(A1, st + 4)
        COMPUTE(A2, st + 2)
    }
#undef LOAD3
#undef COMPUTE

    const size_t xb = (size_t)b * CCH * 1024;
#pragma unroll
    for (int ni = 0; ni < 2; ni++) {
        int p = p0 + ni;
#pragma unroll
        for (int r = 0; r < 16; r++) {
            int fl = (r & 3) + 8 * (r >> 2) + 4 * klane;
            int f = fbase + fl;
            size_t idx = xb + (size_t)f * 1024 + p * 32 + qcol;
            out[idx] = acc[ni][r] + x[idx] + cb[f];
        }
    }
}

extern "C" void kernel_launch(void* const* d_in, const int* in_sizes, int n_in,
                              void* d_out, int out_size, void* d_ws, size_t ws_size,
                              hipStream_t stream) {
    const float* x     = (const float*)d_in[0];
    const float* z     = (const float*)d_in[1];
    const float* dw    = (const float*)d_in[2];
    const float* db    = (const float*)d_in[3];
    const float* gamma = (const float*)d_in[4];
    const float* beta  = (const float*)d_in[5];
    const float* cb    = (const float*)d_in[6];
    float* out = (float*)d_out;

    unsigned short* wkn  = (unsigned short*)d_ws;                                       // 9.44 MB
    unsigned short* wkt  = (unsigned short*)((char*)d_ws + (size_t)BSZ * NB * 2);       // 9.44 MB
    unsigned short* xb16 = (unsigned short*)((char*)d_ws + (size_t)BSZ * NB * 4);       // 8.4 MB

    hyper_mfma<<<NB / 128, 64, 0, stream>>>(z, dw, db, gamma, beta, wkn);
    repack_xt<<<256 + 1024, 256, 0, stream>>>(wkn, wkt, x, xb16);
    conv_mfma<<<1024, 128, 0, stream>>>(x, xb16, wkt, cb, out);
}

// Round 4
// 261.679 us; speedup vs baseline: 1.0152x; 1.0152x over previous
//
#include <hip/hip_runtime.h>

#define NB 147456   // C*C*KH*KW per sample
#define ZD 256
#define BSZ 32
#define CCH 128

typedef __attribute__((ext_vector_type(8))) short short8;
typedef __attribute__((ext_vector_type(16))) float floatx16;

__device__ __forceinline__ unsigned short f2bf(float f) {
    unsigned int u = __float_as_uint(f);
    return (unsigned short)((u + 0x7fffu + ((u >> 16) & 1u)) >> 16);
}
// pack hi16(lo),hi16(hi) -> one dword (two bf16, truncating convert)
__device__ __forceinline__ unsigned pk(unsigned hi, unsigned lo) {
    return __builtin_amdgcn_perm(hi, lo, 0x07060302u);
}

// ---- K1: h = relu(z@W+b); BN over batch; affine; bf16 Wk natural [b][n] -----------------------
// MFMA 32x32x16, M=32 batch. 2304 blocks x 64 cols = 9 blocks/CU EXACT (no dispatch tail; was
// 1152x128 = 4.5/CU, 11% tail on the one HBM-dominant kernel). z streamed per-step (depth-2,
// same rotation as B) to keep VGPR <= 128 so 4 waves/SIMD fit -> 9 resident blocks/CU legal.
// B loads dwordx2: 256 B contiguous/instr, coalescing-fine. BW floor ~24 us (151 MB dw read).
__global__ __launch_bounds__(64, 4) void hyper_mfma(
    const float* __restrict__ z, const float* __restrict__ dw,
    const float* __restrict__ db, const float* __restrict__ gamma,
    const float* __restrict__ beta, unsigned short* __restrict__ wkn)
{
    int lane = threadIdx.x;                   // one wave per block
    int L = lane & 31;
    int klane = lane >> 5;
    int n0 = blockIdx.x * 64 + 2 * L;         // this lane's col pair; tile t owns n0+t

    const float* zp  = z + L * 256 + klane * 8;
    const float* dwp = dw + (size_t)(klane * 8) * NB + n0;

    floatx16 acc[2];
#pragma unroll
    for (int t = 0; t < 2; t++)
#pragma unroll
        for (int r = 0; r < 16; r++) acc[t][r] = 0.f;

    float4 za[2], zb[2];
    unsigned ba[8][2], bb[8][2];
#define LOADZ(BUF, S)                                                         \
    { BUF[0] = *(const float4*)(zp + (S) * 16);                               \
      BUF[1] = *(const float4*)(zp + (S) * 16 + 4); }
#define LOADB(BUF, S)                                                         \
    _Pragma("unroll") for (int j = 0; j < 8; j++)                             \
        *(uint2*)&BUF[j][0] = *(const uint2*)(dwp + (size_t)((S) * 16 + j) * NB);
#define DOMFMA(ZBUF, BUF, S)                                                  \
    {                                                                         \
        uint4 au;                                                             \
        au.x = pk(__float_as_uint(ZBUF[0].y), __float_as_uint(ZBUF[0].x));    \
        au.y = pk(__float_as_uint(ZBUF[0].w), __float_as_uint(ZBUF[0].z));    \
        au.z = pk(__float_as_uint(ZBUF[1].y), __float_as_uint(ZBUF[1].x));    \
        au.w = pk(__float_as_uint(ZBUF[1].w), __float_as_uint(ZBUF[1].z));    \
        short8 af = *(short8*)&au;                                            \
        _Pragma("unroll") for (int t = 0; t < 2; t++) {                       \
            uint4 u;                                                          \
            u.x = pk(BUF[1][t], BUF[0][t]); u.y = pk(BUF[3][t], BUF[2][t]);   \
            u.z = pk(BUF[5][t], BUF[4][t]); u.w = pk(BUF[7][t], BUF[6][t]);   \
            acc[t] = __builtin_amdgcn_mfma_f32_32x32x16_bf16(                 \
                af, *(short8*)&u, acc[t], 0, 0, 0);                           \
        }                                                                     \
    }
    LOADZ(za, 0)
    LOADB(ba, 0)
#pragma unroll
    for (int s = 0; s < 16; s += 2) {
        LOADZ(zb, s + 1)
        LOADB(bb, s + 1)
        DOMFMA(za, ba, s)
        if (s + 2 < 16) { LOADZ(za, s + 2) LOADB(ba, s + 2) }
        DOMFMA(zb, bb, s + 1)
    }
#undef LOADZ
#undef LOADB
#undef DOMFMA

    // BN epilogue per tile-column; rows split between lane and lane^32
    float2 bias = *(const float2*)(db + n0);
    float2 gmm  = *(const float2*)(gamma + n0);
    float2 btt  = *(const float2*)(beta + n0);
    float bias_a[2] = { bias.x, bias.y };
    float gm_a[2]   = { gmm.x, gmm.y };
    float bt_a[2]   = { btt.x, btt.y };

    float sc_a[2], mn_a[2];
#pragma unroll
    for (int t = 0; t < 2; t++) {
        float sp = 0.f, qp = 0.f;
#pragma unroll
        for (int r = 0; r < 16; r++) {
            float v = fmaxf(acc[t][r] + bias_a[t], 0.f);
            acc[t][r] = v;
            sp += v; qp += v * v;
        }
        sp += __shfl_xor(sp, 32, 64);
        qp += __shfl_xor(qp, 32, 64);
        float mn = sp * (1.f / 32.f);
        float var = fmaxf(qp * (1.f / 32.f) - mn * mn, 0.f);
        mn_a[t] = mn;
        sc_a[t] = gm_a[t] / (sqrtf(var) + 1e-6f);
    }

#pragma unroll
    for (int r = 0; r < 16; r++) {
        int brow = (r & 3) + 8 * (r >> 2) + 4 * klane;
        float w0 = sc_a[0] * (acc[0][r] - mn_a[0]) + bt_a[0];
        float w1 = sc_a[1] * (acc[1][r] - mn_a[1]) + bt_a[1];
        unsigned o = (unsigned)f2bf(w0) | ((unsigned)f2bf(w1) << 16);
        *(unsigned*)&wkn[(size_t)brow * NB + n0] = o;
    }
}

// ---- fused: blocks 0..255 repack wkn->wkt; blocks 256..1279 transpose x -> xT bf16 -----------
// wkt layout: [b][uv][ko(16 s-chunks)][f(128)] short8 -> conv A-loads fully coalesced (512B runs)
// xb16 layout: [b][p][ch(16 s-chunks)][q(32)] short8 -> conv LDS staging + reads conflict-free
__global__ __launch_bounds__(256) void repack_xt(
    const unsigned short* __restrict__ wkn, unsigned short* __restrict__ wkt,
    const float* __restrict__ x, unsigned short* __restrict__ xb16)
{
    __shared__ char lmem[16 * 580 * 4];
    int t = threadIdx.x;
    if (blockIdx.x < 256) {
        unsigned int* lt = (unsigned int*)lmem;   // [16][580]
        int b = blockIdx.x >> 3;
        int s0 = (blockIdx.x & 7) * 16;
        const unsigned int* src = (const unsigned int*)wkn + ((size_t)b * NB >> 1) + (size_t)s0 * 576;
#pragma unroll
        for (int i = 0; i < 36; i++) {
            int idx = t + i * 256;
            int si = idx / 576;
            int j2 = idx - si * 576;
            lt[si * 580 + j2] = src[(size_t)si * 576 + j2];
        }
        __syncthreads();
        const unsigned short* ls = (const unsigned short*)lt;
#pragma unroll
        for (int i = 0; i < 9; i++) {
            int tau = t + i * 256;                // 0..2303
            int f = tau & 127;                    // lane-consecutive -> coalesced write
            int half = (tau >> 7) & 1;
            int uv = tau >> 8;                    // 0..8
            int col = f * 9 + uv;
            unsigned short v[8];
#pragma unroll
            for (int ss = 0; ss < 8; ss++)
                v[ss] = ls[(half * 8 + ss) * 1160 + col];
            uint4 o;
            o.x = v[0] | ((unsigned)v[1] << 16);
            o.y = v[2] | ((unsigned)v[3] << 16);
            o.z = v[4] | ((unsigned)v[5] << 16);
            o.w = v[6] | ((unsigned)v[7] << 16);
            ((uint4*)wkt)[((((size_t)b * 9 + uv) * 16) + (s0 >> 3) + half) * 128 + f] = o;
        }
    } else {
        unsigned short* lx = (unsigned short*)lmem;   // [32][130]
        int idx = blockIdx.x - 256;
        int p = idx & 31;
        int b = idx >> 5;
        const float* xp = x + (size_t)b * CCH * 1024 + p * 32;
#pragma unroll
        for (int i = 0; i < 16; i++) {
            int ii = t + i * 256;
            int s = ii >> 5;
            int q = ii & 31;
            lx[q * 130 + s] = f2bf(xp[(size_t)s * 1024 + q]);
        }
        __syncthreads();
#pragma unroll
        for (int i = 0; i < 2; i++) {
            int tau = t + i * 256;                // 0..511
            int q = tau & 31;                     // lane-consecutive -> coalesced write
            int ch = tau >> 5;                    // 0..15
            const unsigned short* r = &lx[q * 130 + ch * 8];
            uint4 o;
            o.x = r[0] | ((unsigned)r[1] << 16);
            o.y = r[2] | ((unsigned)r[3] << 16);
            o.z = r[4] | ((unsigned)r[5] << 16);
            o.w = r[6] | ((unsigned)r[7] << 16);
            ((uint4*)xb16)[(((size_t)b * 32 + p) * 16 + ch) * 32 + q] = o;
        }
    }
}

// ---- conv: 1024 blocks (4/CU), 256 thr = 4 waves = 4 f-quarters, p-tile = 1 row ---------------
// (R2 winner config, reverted after R3's 2-wave variant was neutral-negative.)
// LDS [r=3][ch=16][col=34] (25.5 KB): 4 blocks/CU -> 4 waves/SIMD. br reads are canonical
// contiguous b128 -> conflict-free. A-loads fully coalesced from [b][uv][ko][f] wkt; wkt slice
// L2-resident per XCD (1.2 MB). Depth-1 double-buffered A.
__global__ __launch_bounds__(256, 4) void conv_mfma(
    const float* __restrict__ x, const unsigned short* __restrict__ xb16,
    const unsigned short* __restrict__ wkt, const float* __restrict__ cb,
    float* __restrict__ out)
{
    __shared__ short8 lds8[3 * 16 * 34];      // [r=3][ch=16][col=34]
    int t = threadIdx.x;
    int w = blockIdx.x;                       // 1024 blocks
    int xcd = w & 7, slot = w >> 3;           // 128 slots/XCD
    int b = (xcd << 2) | (slot & 3);          // 4 samples/XCD
    int p0 = slot >> 2;                       // 0..31, one output row per block
    int wid = t >> 6, lane = t & 63;
    int fbase = wid * 32;                     // each wave owns a distinct f-quarter
    int qcol = lane & 31, klane = lane >> 5;

    if (t < 96) {                             // zero halo cols 0 and 33 (3 rows x 16 ch x 2)
        int r = t >> 5;
        int ch = (t >> 1) & 15;
        int col = (t & 1) * 33;
        short8 zz = { 0, 0, 0, 0, 0, 0, 0, 0 };
        lds8[(r * 16 + ch) * 34 + col] = zz;
    }
    const uint4* xsrc = (const uint4*)xb16;
#pragma unroll
    for (int i = 0; i < 6; i++) {             // stage 3 rows x 16 ch x 32 q = 1536 uint4
        int tau = t + i * 256;
        int q = tau & 31;
        int ch = (tau >> 5) & 15;
        int r = tau >> 9;                     // 0..2
        int prow = p0 - 1 + r;
        uint4 v = make_uint4(0, 0, 0, 0);
        if (prow >= 0 && prow < 32)
            v = xsrc[(((size_t)b * 32 + prow) * 16 + ch) * 32 + q];
        *(uint4*)&lds8[(r * 16 + ch) * 34 + q + 1] = v;
    }
    __syncthreads();

    floatx16 acc;
#pragma unroll
    for (int r = 0; r < 16; r++) acc[r] = 0.f;

    const short8* A8 = (const short8*)wkt + ((size_t)b * 9 << 11);
    short8 Abuf0[3], Abuf1[3];

#define LOAD3(BUF, ST)                                                        \
    {                                                                         \
        int v_ = (ST) >> 3, ks_ = (ST) & 7;                                   \
        int ko_ = ks_ * 2 + klane;                                            \
        _Pragma("unroll") for (int u_ = 0; u_ < 3; u_++)                      \
            BUF[u_] = A8[(((size_t)(u_ * 3 + v_) * 16 + ko_) << 7) + fbase + qcol]; \
    }
#define COMPUTE(BUF, ST)                                                      \
    {                                                                         \
        int v_ = (ST) >> 3, ks_ = (ST) & 7;                                   \
        int ko_ = ks_ * 2 + klane;                                            \
        short8 br[3];                                                         \
        _Pragma("unroll") for (int u_ = 0; u_ < 3; u_++)                      \
            br[u_] = lds8[(u_ * 16 + ko_) * 34 + qcol + v_];                  \
        _Pragma("unroll") for (int u_ = 0; u_ < 3; u_++)                      \
            acc = __builtin_amdgcn_mfma_f32_32x32x16_bf16(                    \
                BUF[u_], br[u_], acc, 0, 0, 0);                               \
    }

    LOAD3(Abuf0, 0)
    for (int st = 0; st < 24; st += 2) {
        LOAD3(Abuf1, st + 1)
        COMPUTE(Abuf0, st)
        if (st + 2 < 24) LOAD3(Abuf0, st + 2)
        COMPUTE(Abuf1, st + 1)
    }
#undef LOAD3
#undef COMPUTE

    const size_t xb = (size_t)b * CCH * 1024;
#pragma unroll
    for (int r = 0; r < 16; r++) {
        int fl = (r & 3) + 8 * (r >> 2) + 4 * klane;
        int f = fbase + fl;
        size_t idx = xb + (size_t)f * 1024 + p0 * 32 + qcol;
        out[idx] = acc[r] + x[idx] + cb[f];
    }
}

extern "C" void kernel_launch(void* const* d_in, const int* in_sizes, int n_in,
                              void* d_out, int out_size, void* d_ws, size_t ws_size,
                              hipStream_t stream) {
    const float* x     = (const float*)d_in[0];
    const float* z     = (const float*)d_in[1];
    const float* dw    = (const float*)d_in[2];
    const float* db    = (const float*)d_in[3];
    const float* gamma = (const float*)d_in[4];
    const float* beta  = (const float*)d_in[5];
    const float* cb    = (const float*)d_in[6];
    float* out = (float*)d_out;

    unsigned short* wkn  = (unsigned short*)d_ws;                                       // 9.44 MB
    unsigned short* wkt  = (unsigned short*)((char*)d_ws + (size_t)BSZ * NB * 2);       // 9.44 MB
    unsigned short* xb16 = (unsigned short*)((char*)d_ws + (size_t)BSZ * NB * 4);       // 8.4 MB

    hyper_mfma<<<NB / 64, 64, 0, stream>>>(z, dw, db, gamma, beta, wkn);
    repack_xt<<<256 + 1024, 256, 0, stream>>>(wkn, wkt, x, xb16);
    conv_mfma<<<1024, 256, 0, stream>>>(x, xb16, wkt, cb, out);
}